// Round 1
// baseline (3608.080 us; speedup 1.0000x reference)
//
#include <hip/hip_runtime.h>

#define BB 256
#define LL 2048
#define DIN 128
#define DOUT 128
#define T 32   // timesteps per chunk
#define TT 16  // per-thread t-range in projection phase (T/2)

__device__ __forceinline__ float tanh_fast(float v) {
    // algebraically exact: tanh(v) = 1 - 2/(exp(2v)+1); abs err ~1e-7
    float e = __expf(2.0f * v);
    return 1.0f - 2.0f / (e + 1.0f);
}

__global__ __launch_bounds__(256, 1)
void rwa_fused(const float* __restrict__ x, const float* __restrict__ s0,
               const float* __restrict__ u_w, const float* __restrict__ u_b,
               const float* __restrict__ g_w, const float* __restrict__ g_b,
               const float* __restrict__ a_w, float* __restrict__ out)
{
    __shared__ float x_sh[T * DIN];     // 16 KB
    __shared__ float pU[T * DOUT];      // 16 KB
    __shared__ float pG[T * DOUT];      // 16 KB
    __shared__ float pA[T * DOUT];      // 16 KB
    __shared__ float h_sh[DOUT];
    __shared__ float alin_sh[DOUT];

    const int tid = threadIdx.x;
    const int o   = tid & 127;
    const int grp = tid >> 7;           // 0: g-side, 1: a-side
    const int b   = blockIdx.x;

    // ---- recurrence weight row for this thread, held in VGPRs ----
    // grp0: g_wh[o][:]  (g_w[o, DIN:]) ; grp1: a_wh[o][:] (a_w[o, DIN:])
    float4 wreg[32];
    {
        const float* wbase = (grp == 0 ? g_w : a_w) + (size_t)o * (DIN + DOUT) + DIN;
        const float4* wsrc = (const float4*)wbase;
        #pragma unroll
        for (int i = 0; i < 32; i++) wreg[i] = wsrc[i];
    }
    const float ub = u_b[o];
    const float gb = g_b[o];

    // ---- init state ----
    float num = 0.0f, den = 0.0f, amax = 1e-38f;
    if (tid < DOUT) h_sh[tid] = tanh_fast(s0[tid]);
    __syncthreads();

    const float4* u4 = (const float4*)(u_w + (size_t)o * DIN);
    const float4* g4 = (const float4*)(g_w + (size_t)o * (DIN + DOUT));
    const float4* a4 = (const float4*)(a_w + (size_t)o * (DIN + DOUT));

    for (int t0 = 0; t0 < LL; t0 += T) {
        // ---- stage x chunk: x[b, t0..t0+T, :] -> LDS (coalesced float4) ----
        {
            const float4* xg = (const float4*)(x + ((size_t)b * LL + t0) * DIN);
            float4* xs = (float4*)x_sh;
            #pragma unroll
            for (int i = 0; i < (T * DIN / 4) / 256; i++)   // 4 iters
                xs[tid + 256 * i] = xg[tid + 256 * i];
        }
        __syncthreads();

        // ---- projections: thread (o, grp) computes rows o of U/Gx/Ax for
        //      t in [grp*TT, grp*TT+TT). x reads are wave-uniform broadcasts.
        {
            float accU[TT], accG[TT], accA[TT];
            #pragma unroll
            for (int tt = 0; tt < TT; tt++) { accU[tt] = ub; accG[tt] = gb; accA[tt] = 0.0f; }
            const float4* xs4 = (const float4*)x_sh + (size_t)(grp * TT) * 32;
            #pragma unroll 2
            for (int k4 = 0; k4 < 32; k4++) {
                float4 wu = u4[k4], wg = g4[k4], wa = a4[k4];
                #pragma unroll
                for (int tt = 0; tt < TT; tt++) {
                    float4 xv = xs4[tt * 32 + k4];
                    accU[tt] = fmaf(wu.x, xv.x, fmaf(wu.y, xv.y, fmaf(wu.z, xv.z, fmaf(wu.w, xv.w, accU[tt]))));
                    accG[tt] = fmaf(wg.x, xv.x, fmaf(wg.y, xv.y, fmaf(wg.z, xv.z, fmaf(wg.w, xv.w, accG[tt]))));
                    accA[tt] = fmaf(wa.x, xv.x, fmaf(wa.y, xv.y, fmaf(wa.z, xv.z, fmaf(wa.w, xv.w, accA[tt]))));
                }
            }
            #pragma unroll
            for (int tt = 0; tt < TT; tt++) {
                int t = grp * TT + tt;
                pU[t * DOUT + o] = accU[tt];
                pG[t * DOUT + o] = accG[tt];
                pA[t * DOUT + o] = accA[tt];
            }
        }
        __syncthreads();

        // ---- sequential recurrence over this chunk ----
        for (int ts = 0; ts < T; ts++) {
            // both groups: dot(wrow, h) ; h reads are wave-uniform broadcasts
            float ax0 = 0.f, ax1 = 0.f, ax2 = 0.f, ax3 = 0.f;
            const float4* h4 = (const float4*)h_sh;
            #pragma unroll
            for (int k4 = 0; k4 < 32; k4++) {
                float4 hv = h4[k4];
                ax0 = fmaf(wreg[k4].x, hv.x, ax0);
                ax1 = fmaf(wreg[k4].y, hv.y, ax1);
                ax2 = fmaf(wreg[k4].z, hv.z, ax2);
                ax3 = fmaf(wreg[k4].w, hv.w, ax3);
            }
            float dot = (ax0 + ax1) + (ax2 + ax3);
            if (grp == 1) alin_sh[o] = dot;
            __syncthreads();   // a_lin ready; all h_sh reads complete
            if (grp == 0) {
                float g = tanh_fast(pG[ts * DOUT + o] + dot);
                float z = pU[ts * DOUT + o] * g;
                float a = pA[ts * DOUT + o] + alin_sh[o];
                float amn = fmaxf(a, amax);
                float e = __expf(amn - amax);
                amax = amn;
                num = fmaf(z, e, num);
                den += e;
                float h = tanh_fast(num / den);
                h_sh[o] = h;
                out[((size_t)b * LL + (t0 + ts)) * DOUT + o] = h;
            }
            __syncthreads();   // h ready for next step
        }
    }
}

extern "C" void kernel_launch(void* const* d_in, const int* in_sizes, int n_in,
                              void* d_out, int out_size, void* d_ws, size_t ws_size,
                              hipStream_t stream) {
    const float* x   = (const float*)d_in[0];
    const float* s0  = (const float*)d_in[1];
    const float* u_w = (const float*)d_in[2];
    const float* u_b = (const float*)d_in[3];
    const float* g_w = (const float*)d_in[4];
    const float* g_b = (const float*)d_in[5];
    const float* a_w = (const float*)d_in[6];
    float* out = (float*)d_out;
    rwa_fused<<<BB, 256, 0, stream>>>(x, s0, u_w, u_b, g_w, g_b, a_w, out);
}